// Round 5
// baseline (825.690 us; speedup 1.0000x reference)
//
#include <hip/hip_runtime.h>
#include <math.h>

#define BB 4
#define CC 64
#define NN 8192
#define OO 128
#define KK 20
#define DD 128            // 2*CC
#define BUFSZ 15          // per-lane append buffer (checked twice per tile: cnt<=7 -> +8 max)

typedef short bf16x8 __attribute__((ext_vector_type(8)));   // 8 bf16 (4 VGPR)
typedef float f32x4 __attribute__((ext_vector_type(4)));
typedef unsigned short u16x8 __attribute__((ext_vector_type(8)));
typedef unsigned long long u64;

typedef __attribute__((address_space(1))) const void gvoid;
typedef __attribute__((address_space(3))) void lvoid;

// orderable-key packing: (float value, candidate idx) -> u64, so that
// u64-descending == (value desc, idx asc). Matches jax.lax.top_k tie-breaking.
__device__ __forceinline__ u64 packkey(float v, int idx) {
  unsigned u = __float_as_uint(v);
  unsigned o = ((int)u < 0) ? ~u : (u | 0x80000000u);
  return (((u64)o) << 32) | (unsigned)(~idx);
}
__device__ __forceinline__ float keyval(u64 k) {
  unsigned o = (unsigned)(k >> 32);
  unsigned u = (o & 0x80000000u) ? (o ^ 0x80000000u) : ~o;
  return __uint_as_float(u);
}
#define INITKEY (((u64)0x007FFFFFu) << 32)   // packkey(-inf, 0xFFFFFFFF)

__device__ __forceinline__ unsigned short bf_rne(float f) {
  unsigned u = __float_as_uint(f);
  u += 0x7FFFu + ((u >> 16) & 1u);
  return (unsigned short)(u >> 16);
}
__device__ __forceinline__ float bf_f(unsigned short h) {
  return __uint_as_float(((unsigned)h) << 16);
}

// ---------------------------------------------------------------------------
// prep: xx[b][n] and xs[b][n][192] = 3-way bf16 split [h(64)|m(64)|l(64)],
// PRE-SWIZZLED: 16B-group at logical byte o lands at o ^ ((n&7)<<4).
// (unchanged)
// ---------------------------------------------------------------------------
__global__ __launch_bounds__(128) void prep_kernel(const float* __restrict__ x,
                                                   float* __restrict__ xx,
                                                   unsigned short* __restrict__ xs) {
  const int tid = threadIdx.x;
  const int b = blockIdx.y;
  const int n0 = blockIdx.x * 128;
  const float* xb = x + (size_t)b * CC * NN;
  float xv[CC];
  float acc = 0.0f;
  #pragma unroll
  for (int c = 0; c < CC; ++c) {
    float v = xb[(size_t)c * NN + n0 + tid];   // coalesced over tid
    acc += v * v;
    xv[c] = v;
  }
  xx[b * NN + n0 + tid] = acc;

  const int n = n0 + tid;
  char* xsrow = ((char*)xs) + ((size_t)b * NN + n) * 384;
  const int swn = (n & 7) << 4;
  #pragma unroll
  for (int gr = 0; gr < 8; ++gr) {
    u16x8 h8, m8, l8;
    #pragma unroll
    for (int e = 0; e < 8; ++e) {
      float v = xv[gr * 8 + e];
      unsigned short h = bf_rne(v);
      float r = v - bf_f(h);
      unsigned short m = bf_rne(r);
      r -= bf_f(m);
      unsigned short l = bf_rne(r);
      h8[e] = (unsigned short)h; m8[e] = m; l8[e] = l;
    }
    *(u16x8*)(xsrow + (((gr * 16) + 0) ^ swn)) = h8;
    *(u16x8*)(xsrow + (((gr * 16) + 128) ^ swn)) = m8;
    *(u16x8*)(xsrow + (((gr * 16) + 256) ^ swn)) = l8;
  }
}

// ---------------------------------------------------------------------------
// knn: MFMA distance matrix + per-lane buffered top-20.
// ROUND-5 CHANGE (post-mortem of r4: dbuf+setprio moved nothing -> stall is
// NOT staging latency; revised theory = serial MFMA accumulator chain, 18
// dependent MFMAs at ~18cyc latency vs ~5cyc throughput with only 2
// waves/SIMD to cover): hoist all 24 A-frag ds_reads (grouped by c6 so the
// first quad of chains starts after 4 reads), then run the FOUR subtile
// chains INTERLEAVED -> dependency distance 4 ~= latency/throughput, matrix
// pipe saturable per-wave. Per-chain op order (s=2..0, c6=0..5) bit-identical
// to the verified kernel; pd/append order and rebuild trigger points
// unchanged -> selection bit-identical.
// ---------------------------------------------------------------------------
__global__ __launch_bounds__(256, 2) void knn_kernel(
    const unsigned short* __restrict__ xs, const float* __restrict__ xx,
    int* __restrict__ fidx) {
  __shared__ __attribute__((aligned(16))) unsigned short atile[2][64 * 192]; // 49152 B
  __shared__ float cxx[2][64];                                               //   512 B
  __shared__ u64 abuf[4][64][BUFSZ];                                         // 30720 B
                                                                             // total 80384 B
  const int tid = threadIdx.x;
  const int w = tid >> 6;
  const int lane = tid & 63;
  const int r = lane & 15;    // query col (B) / cand row (A) within subtile
  const int g = lane >> 4;    // k-group
  const int b = blockIdx.y;
  const int qbase = blockIdx.x * 64 + w * 16;
  const int q = qbase + r;
  const char* xsb = ((const char*)xs) + (size_t)b * NN * 384;

  // query B-frags: bq[split][k-chunk]; lane holds k = (lane>>4)*8+[0..8) of 32
  bf16x8 bq[3][2];
  {
    const char* qrow = xsb + (size_t)q * 384;
    const int sw = (q & 7) << 4;
    #pragma unroll
    for (int s = 0; s < 3; ++s)
      #pragma unroll
      for (int c = 0; c < 2; ++c)
        bq[s][c] = *(const bf16x8*)(qrow + ((s * 128 + c * 64 + g * 16) ^ sw));
  }
  const float xxq = xx[b * NN + q];

  u64 tk[KK];
  #pragma unroll
  for (int j = 0; j < KK; ++j) tk[j] = INITKEY;
  float minv = -INFINITY;
  int cnt = 0;
  u64* mybuf = &abuf[w][lane][0];

  // stage tile t into buffer p
  auto stage = [&](int t, int p) {
    const char* src = xsb + (size_t)t * 64 * 384;
    char* dst = (char*)atile[p];
    #pragma unroll
    for (int it = 0; it < 6; ++it) {
      __builtin_amdgcn_global_load_lds(
          (gvoid*)(src + it * 4096 + tid * 16),
          (lvoid*)(dst + it * 4096 + tid * 16), 16, 0, 0);
    }
    if (tid < 16) {
      __builtin_amdgcn_global_load_lds(
          (gvoid*)(xx + b * NN + t * 64 + tid * 4),
          (lvoid*)(cxx[p] + tid * 4), 16, 0, 0);
    }
  };

  // fold buffered candidates into the register-sorted top-20, tighten minv
  auto rebuild = [&]() {
    int mxc = cnt;
    #pragma unroll
    for (int o = 32; o > 0; o >>= 1) {
      int v = __shfl_xor(mxc, o);
      mxc = mxc > v ? mxc : v;
    }
    for (int i = 0; i < mxc; ++i) {
      u64 k = (i < cnt) ? mybuf[i] : 0ULL;
      if (k > tk[KK - 1]) {
        #pragma unroll
        for (int jj = KK - 1; jj >= 1; --jj)
          tk[jj] = (k > tk[jj - 1]) ? tk[jj - 1] : ((k > tk[jj]) ? k : tk[jj]);
        tk[0] = (k > tk[0]) ? k : tk[0];
      }
    }
    cnt = 0;
    minv = keyval(tk[KK - 1]);
  };

  stage(0, 0);
  __syncthreads();

  for (int t = 0; t < NN / 64; ++t) {
    const int p = t & 1;
    if (t < NN / 64 - 1) stage(t + 1, p ^ 1);   // in flight during compute

    // --- hoist ALL subtile A-frags (24 ds_read_b128), c6-major so the
    //     first 4 reads unblock the first MFMA quad ---
    const int sw = (r & 7) << 4;
    const char* tbase = (const char*)atile[p];
    bf16x8 a[4][6];
    #pragma unroll
    for (int c6 = 0; c6 < 6; ++c6) {
      const int off = (c6 * 64 + g * 16) ^ sw;
      #pragma unroll
      for (int ct = 0; ct < 4; ++ct)
        a[ct][c6] = *(const bf16x8*)(tbase + (ct * 16 + r) * 384 + off);
    }

    // --- 4 independent accumulator chains, interleaved (dep distance 4) ---
    f32x4 acc[4];
    #pragma unroll
    for (int ct = 0; ct < 4; ++ct) acc[ct] = (f32x4){0.f, 0.f, 0.f, 0.f};
    __builtin_amdgcn_s_setprio(1);
    #pragma unroll
    for (int s = 2; s >= 0; --s)       // b-split l,m first: small terms first
      #pragma unroll
      for (int c6 = 0; c6 < 6; ++c6) {
        const bf16x8 bqf = bq[s][c6 & 1];
        #pragma unroll
        for (int ct = 0; ct < 4; ++ct)
          acc[ct] = __builtin_amdgcn_mfma_f32_16x16x32_bf16(a[ct][c6], bqf,
                                                            acc[ct], 0, 0, 0);
      }
    __builtin_amdgcn_s_setprio(0);

    // --- pd + append (order identical to r3/r4), rebuild between halves ---
    #pragma unroll
    for (int half = 0; half < 2; ++half) {
      #pragma unroll
      for (int cth = 0; cth < 2; ++cth) {
        const int ct = half * 2 + cth;
        #pragma unroll
        for (int j = 0; j < 4; ++j) {
          const int ml = ct * 16 + g * 4 + j;
          float pd = (-xxq - (-2.0f * acc[ct][j])) - cxx[p][ml];
          if (pd > minv) { mybuf[cnt] = packkey(pd, t * 64 + ml); ++cnt; }
        }
      }
      // invariant: cnt<=7 entering a subtile pair; <=8 appends per pair
      if (__any(cnt > 7)) rebuild();
    }
    __syncthreads();   // buf[p^1] now resident; buf[p] free for next stage
  }

  rebuild();   // flush remaining buffered candidates

  // --- epilogue: 4-way merge of the per-lane class lists -> fidx ---
  // scratch: atile is dead now (all waves passed the final barrier)
  u64* ml = ((u64*)&atile[0][0]) + (size_t)w * 64 * KK;   // 10240 B per wave
  #pragma unroll
  for (int j = 0; j < KK; ++j) ml[lane * KK + j] = tk[j];
  __syncthreads();
  if (lane < 16) {
    int* fo = fidx + ((size_t)b * NN + qbase + lane) * KK;
    const u64* L0 = ml + (lane + 0) * KK;
    const u64* L1 = ml + (lane + 16) * KK;
    const u64* L2 = ml + (lane + 32) * KK;
    const u64* L3 = ml + (lane + 48) * KK;
    int p0 = 0, p1 = 0, p2 = 0, p3 = 0;
    u64 h0 = L0[0], h1 = L1[0], h2 = L2[0], h3 = L3[0];
    #pragma unroll
    for (int k = 0; k < KK; ++k) {
      u64 bv = h0; int bc = 0;
      if (h1 > bv) { bv = h1; bc = 1; }
      if (h2 > bv) { bv = h2; bc = 2; }
      if (h3 > bv) { bv = h3; bc = 3; }
      fo[k] = (int)(~(unsigned)bv);
      if (bc == 0)      { ++p0; h0 = (p0 < KK) ? L0[p0] : 0ULL; }
      else if (bc == 1) { ++p1; h1 = (p1 < KK) ? L1[p1] : 0ULL; }
      else if (bc == 2) { ++p2; h2 = (p2 < KK) ? L2[p2] : 0ULL; }
      else              { ++p3; h3 = (p3 < KK) ? L3[p3] : 0ULL; }
    }
  }
}

// ---------------------------------------------------------------------------
// w1prep: pre-pack W1a^T as 3-way bf16-split MFMA B-frags. (unchanged)
// ---------------------------------------------------------------------------
__global__ __launch_bounds__(256) void w1prep_kernel(const float* __restrict__ W1,
                                                     unsigned short* __restrict__ w1p) {
  for (int e = threadIdx.x; e < 12288; e += 256) {
    const int f = e >> 9;
    const int rr = e & 511;
    const int l = rr >> 3;
    const int j = rr & 7;
    const int pair = f / 3, s = f % 3;
    const int dt = pair >> 1, kc = pair & 1;
    const int d = dt * 16 + (l & 15);
    const int c = kc * 32 + (l >> 4) * 8 + j;
    const float v = W1[d * DD + c];
    const unsigned short h = bf_rne(v);
    float r = v - bf_f(h);
    const unsigned short m = bf_rne(r);
    r -= bf_f(m);
    const unsigned short lo = bf_rne(r);
    w1p[(size_t)f * 512 + l * 8 + j] = (s == 0) ? h : ((s == 1) ? m : lo);
  }
}

#define MFMA16(A, B, C) __builtin_amdgcn_mfma_f32_16x16x32_bf16((A), (B), (C), 0, 0, 0)

// one h-GEMM cross term (SA = A split, SB = B split), indices compile-time
template <int SA, int SB>
__device__ __forceinline__ void h_term(const bf16x8 (&a)[3][2][2],
                                       const bf16x8 (&w1f)[24],
                                       f32x4 (&acc)[4][2]) {
  #pragma unroll
  for (int dt = 0; dt < 4; ++dt)
    #pragma unroll
    for (int kc = 0; kc < 2; ++kc) {
      const bf16x8 bf = w1f[(dt * 2 + kc) * 3 + SB];
      acc[dt][0] = MFMA16(a[SA][kc][0], bf, acc[dt][0]);
      acc[dt][1] = MFMA16(a[SA][kc][1], bf, acc[dt][1]);
    }
}

// epilogue for d-tile DT: Y re-layout via identity-B MFMA, masked softmax
// over k (shfl_xor across the 4 lane-groups), returns T[d] = sum_k y_k[d]*gate
template <int DT>
__device__ __forceinline__ float d1_epi(const bf16x8 (&a)[3][2][2],
                                        bf16x8 id0, bf16x8 id1,
                                        const f32x4 (&acc)[4][2], int g) {
  constexpr int KC = DT >> 1;
  const bf16x8 idp = (DT & 1) ? id1 : id0;
  f32x4 yf0 = {0.f, 0.f, 0.f, 0.f}, yf1 = {0.f, 0.f, 0.f, 0.f};
  yf0 = MFMA16(a[1][KC][0], idp, yf0);   // m split first (smaller)
  yf0 = MFMA16(a[0][KC][0], idp, yf0);
  yf1 = MFMA16(a[1][KC][1], idp, yf1);
  yf1 = MFMA16(a[0][KC][1], idp, yf1);
  const f32x4 h0 = acc[DT][0], h1 = acc[DT][1];
  float mx = fmaxf(fmaxf(h0[0], h0[1]), fmaxf(h0[2], h0[3]));
  mx = fmaxf(mx, fmaxf(fmaxf(h1[0], h1[1]), fmaxf(h1[2], h1[3])));  // dups harmless
  mx = fmaxf(mx, __shfl_xor(mx, 16));
  mx = fmaxf(mx, __shfl_xor(mx, 32));
  float sl = 0.f, tl = 0.f;
  #pragma unroll
  for (int j = 0; j < 4; ++j) {
    const float e = __expf(h0[j] - mx);
    sl += e; tl += yf0[j] * e;
  }
  if (g == 0) {   // tile1 rows k=16..19 counted exactly once (dup groups masked)
    #pragma unroll
    for (int j = 0; j < 4; ++j) {
      const float e = __expf(h1[j] - mx);
      sl += e; tl += yf1[j] * e;
    }
  }
  sl += __shfl_xor(sl, 16); sl += __shfl_xor(sl, 32);
  tl += __shfl_xor(tl, 16); tl += __shfl_xor(tl, 32);
  return tl / sl;
}

// ---------------------------------------------------------------------------
// d1 (MFMA rewrite; unchanged from round-3 pass).
//   td = z.(W1b-W1a) is k-constant -> cancels in softmax(axis=k): DROPPED.
//   sum_k gate[k][d] = 1 -> g[d>=64] = z[d-64]; g[d<64] = (sum_k y_k[d]*gate)
//   - z[d]. One wave per n, no LDS, no barriers.
// ---------------------------------------------------------------------------
__global__ __launch_bounds__(256, 2) void d1_kernel(
    const unsigned short* __restrict__ xs, const int* __restrict__ fidx,
    const unsigned short* __restrict__ w1p, float* __restrict__ gbuf) {
  const int tid = threadIdx.x;
  const int w = tid >> 6;
  const int lane = tid & 63;
  const int r = lane & 15;
  const int g = lane >> 4;
  const int b = blockIdx.y;
  const char* xsb = ((const char*)xs) + (size_t)b * NN * 384;

  // hoisted n-invariant B-frags (96 VGPR)
  bf16x8 w1f[24];
  #pragma unroll
  for (int f = 0; f < 24; ++f)
    w1f[f] = *(const bf16x8*)(((const char*)w1p) + f * 1024 + lane * 16);

  // identity B-frags: select cols [p*16, p*16+16) of the K=32 chunk
  bf16x8 id0, id1;
  #pragma unroll
  for (int j = 0; j < 8; ++j) {
    id0[j] = (g == (r >> 3) && j == (r & 7)) ? (short)0x3F80 : (short)0;
    id1[j] = (g == 2 + (r >> 3) && j == (r & 7)) ? (short)0x3F80 : (short)0;
  }

  for (int i = 0; i < 4; ++i) {
    const int n = blockIdx.x * 16 + w * 4 + i;
    const size_t ng = (size_t)b * NN + n;
    const int* kp = fidx + ng * KK;
    const int row0 = kp[r];                 // tile0 row r -> neighbor r
    const int row1 = kp[16 + (r & 3)];      // tile1 row r -> neighbor 16+(r&3)
    const char* rp0 = xsb + (size_t)row0 * 384;
    const char* rp1 = xsb + (size_t)row1 * 384;
    const int sw0 = (row0 & 7) << 4, sw1 = (row1 & 7) << 4;

    bf16x8 a[3][2][2];
    #pragma unroll
    for (int s = 0; s < 3; ++s)
      #pragma unroll
      for (int kc = 0; kc < 2; ++kc) {
        const int off = s * 128 + kc * 64 + g * 16;
        a[s][kc][0] = *(const bf16x8*)(rp0 + (off ^ sw0));
        a[s][kc][1] = *(const bf16x8*)(rp1 + (off ^ sw1));
      }

    // z[c=lane] reconstructed to ~2^-27
    const char* zrow = xsb + (size_t)n * 384;
    const int swn = (n & 7) << 4;
    float zl;
    {
      const unsigned short zh = *(const unsigned short*)(zrow + ((2 * lane) ^ swn));
      const unsigned short zm = *(const unsigned short*)(zrow + ((128 + 2 * lane) ^ swn));
      const unsigned short zo = *(const unsigned short*)(zrow + ((256 + 2 * lane) ^ swn));
      zl = bf_f(zh) + bf_f(zm) + bf_f(zo);
    }

    f32x4 acc[4][2];
    #pragma unroll
    for (int dt = 0; dt < 4; ++dt) {
      acc[dt][0] = (f32x4){0.f, 0.f, 0.f, 0.f};
      acc[dt][1] = (f32x4){0.f, 0.f, 0.f, 0.f};
    }
    // smallest cross terms first
    h_term<2, 0>(a, w1f, acc);
    h_term<0, 2>(a, w1f, acc);
    h_term<1, 1>(a, w1f, acc);
    h_term<1, 0>(a, w1f, acc);
    h_term<0, 1>(a, w1f, acc);
    h_term<0, 0>(a, w1f, acc);

    const float t0 = d1_epi<0>(a, id0, id1, acc, g);
    const float t1 = d1_epi<1>(a, id0, id1, acc, g);
    const float t2 = d1_epi<2>(a, id0, id1, acc, g);
    const float t3 = d1_epi<3>(a, id0, id1, acc, g);

    float* go = gbuf + ng * DD;
    go[64 + lane] = zl;                     // g[d>=64] = z  (sum gate == 1)
    const float z0 = __shfl(zl, r);
    const float z1 = __shfl(zl, 16 + r);
    const float z2 = __shfl(zl, 32 + r);
    const float z3 = __shfl(zl, 48 + r);
    if (lane < 16) {
      go[r]      = t0 - z0;
      go[16 + r] = t1 - z1;
      go[32 + r] = t2 - z2;
      go[48 + r] = t3 - z3;
    }
  }
}

// ---------------------------------------------------------------------------
// d2: out[b][o][n] = sum_c g[b][n][c] * W2[o][c]. (unchanged)
// ---------------------------------------------------------------------------
__global__ __launch_bounds__(256) void d2_kernel(const float* __restrict__ gbuf,
                                                 const float* __restrict__ W2,
                                                 float* __restrict__ out) {
  __shared__ float4 w2s[OO * 32];  // addr4 = o*32 + (c4 ^ (o&7))
  const int tid = threadIdx.x;
  const int b = blockIdx.y;
  const int n0 = blockIdx.x * 32;
  const float4* w2v = (const float4*)W2;
  for (int t = tid; t < OO * 32; t += 256) {
    int o = t >> 5, c4 = t & 31;
    w2s[o * 32 + (c4 ^ (o & 7))] = w2v[t];
  }
  __syncthreads();
  const int og = tid & 7;
  const int ni = tid >> 3;
  const int n = n0 + ni;
  const float4* gp = (const float4*)(gbuf + ((size_t)b * NN + n) * DD);
  float acc[16];
  #pragma unroll
  for (int j = 0; j < 16; ++j) acc[j] = 0.0f;
  for (int c4 = 0; c4 < 32; ++c4) {
    float4 g4 = gp[c4];
    #pragma unroll
    for (int j = 0; j < 16; ++j) {
      const int o = j * 8 + og;
      float4 w4 = w2s[o * 32 + (c4 ^ og)];
      acc[j] += g4.x * w4.x + g4.y * w4.y + g4.z * w4.z + g4.w * w4.w;
    }
  }
  float* outb = out + (size_t)b * OO * NN;
  #pragma unroll
  for (int j = 0; j < 16; ++j) {
    outb[(size_t)(j * 8 + og) * NN + n] = acc[j];
  }
}

// ---------------------------------------------------------------------------
// ws layout (bytes):
//   xs   @ 0          : 6,291,456 u16 = 12,582,912 B  (live: prep->knn,d1)
//   xx   @ 12,582,912 :    32,768 f32 =    131,072 B  (live: prep->knn)
//   w1p  @ 12,582,912 :    12,288 u16 =     24,576 B  (aliases dead xx; w1prep->d1)
//   fidx @ 12,713,984 :   655,360 i32 =  2,621,440 B  (live: knn->d1)
//   gbuf @ 15,335,424 : 4,194,304 f32 = 16,777,216 B  (live: d1->d2)
// total: 32,112,640 B
// ---------------------------------------------------------------------------
extern "C" void kernel_launch(void* const* d_in, const int* in_sizes, int n_in,
                              void* d_out, int out_size, void* d_ws, size_t ws_size,
                              hipStream_t stream) {
  const float* x  = (const float*)d_in[0];
  const float* W1 = (const float*)d_in[1];
  const float* W2 = (const float*)d_in[2];
  float* out = (float*)d_out;
  char* ws = (char*)d_ws;
  unsigned short* xs = (unsigned short*)(ws);
  float* xx = (float*)(ws + 12582912);
  unsigned short* w1p = (unsigned short*)(ws + 12582912);
  int* fidx = (int*)(ws + 12713984);
  float* gbuf = (float*)(ws + 15335424);

  prep_kernel<<<dim3(NN / 128, BB), 128, 0, stream>>>(x, xx, xs);
  knn_kernel<<<dim3(NN / 64, BB), 256, 0, stream>>>(xs, xx, fidx);
  w1prep_kernel<<<dim3(1), 256, 0, stream>>>(W1, w1p);   // after knn: xx dead
  d1_kernel<<<dim3(NN / 16, BB), 256, 0, stream>>>(xs, fidx, w1p, gbuf);
  d2_kernel<<<dim3(NN / 32, BB), 256, 0, stream>>>(gbuf, W2, out);
}

// Round 6
// 820.439 us; speedup vs baseline: 1.0064x; 1.0064x over previous
//
#include <hip/hip_runtime.h>
#include <math.h>

#define BB 4
#define CC 64
#define NN 8192
#define OO 128
#define KK 20
#define DD 128            // 2*CC
#define BUFSZ 15          // per-lane append buffer (checked twice per tile: cnt<=7 -> +8 max)

typedef short bf16x8 __attribute__((ext_vector_type(8)));   // 8 bf16 (4 VGPR)
typedef float f32x4 __attribute__((ext_vector_type(4)));
typedef unsigned short u16x8 __attribute__((ext_vector_type(8)));
typedef unsigned long long u64;

typedef __attribute__((address_space(1))) const void gvoid;
typedef __attribute__((address_space(3))) void lvoid;

// orderable-key packing: (float value, candidate idx) -> u64, so that
// u64-descending == (value desc, idx asc). Matches jax.lax.top_k tie-breaking.
__device__ __forceinline__ u64 packkey(float v, int idx) {
  unsigned u = __float_as_uint(v);
  unsigned o = ((int)u < 0) ? ~u : (u | 0x80000000u);
  return (((u64)o) << 32) | (unsigned)(~idx);
}
__device__ __forceinline__ float keyval(u64 k) {
  unsigned o = (unsigned)(k >> 32);
  unsigned u = (o & 0x80000000u) ? (o ^ 0x80000000u) : ~o;
  return __uint_as_float(u);
}
#define INITKEY (((u64)0x007FFFFFu) << 32)   // packkey(-inf, 0xFFFFFFFF)

__device__ __forceinline__ unsigned short bf_rne(float f) {
  unsigned u = __float_as_uint(f);
  u += 0x7FFFu + ((u >> 16) & 1u);
  return (unsigned short)(u >> 16);
}
__device__ __forceinline__ float bf_f(unsigned short h) {
  return __uint_as_float(((unsigned)h) << 16);
}

// ---------------------------------------------------------------------------
// prep: xx[b][n] and xs[b][n][192] = 3-way bf16 split [h(64)|m(64)|l(64)],
// PRE-SWIZZLED: 16B-group at logical byte o lands at o ^ ((n&7)<<4).
// (unchanged)
// ---------------------------------------------------------------------------
__global__ __launch_bounds__(128) void prep_kernel(const float* __restrict__ x,
                                                   float* __restrict__ xx,
                                                   unsigned short* __restrict__ xs) {
  const int tid = threadIdx.x;
  const int b = blockIdx.y;
  const int n0 = blockIdx.x * 128;
  const float* xb = x + (size_t)b * CC * NN;
  float xv[CC];
  float acc = 0.0f;
  #pragma unroll
  for (int c = 0; c < CC; ++c) {
    float v = xb[(size_t)c * NN + n0 + tid];   // coalesced over tid
    acc += v * v;
    xv[c] = v;
  }
  xx[b * NN + n0 + tid] = acc;

  const int n = n0 + tid;
  char* xsrow = ((char*)xs) + ((size_t)b * NN + n) * 384;
  const int swn = (n & 7) << 4;
  #pragma unroll
  for (int gr = 0; gr < 8; ++gr) {
    u16x8 h8, m8, l8;
    #pragma unroll
    for (int e = 0; e < 8; ++e) {
      float v = xv[gr * 8 + e];
      unsigned short h = bf_rne(v);
      float r = v - bf_f(h);
      unsigned short m = bf_rne(r);
      r -= bf_f(m);
      unsigned short l = bf_rne(r);
      h8[e] = (unsigned short)h; m8[e] = m; l8[e] = l;
    }
    *(u16x8*)(xsrow + (((gr * 16) + 0) ^ swn)) = h8;
    *(u16x8*)(xsrow + (((gr * 16) + 128) ^ swn)) = m8;
    *(u16x8*)(xsrow + (((gr * 16) + 256) ^ swn)) = l8;
  }
}

// ---------------------------------------------------------------------------
// knn: MFMA distance matrix + per-lane buffered top-20.
// ROUND-6 CHANGE (post-mortem r3/r4/r5: three different schedules all pinned
// at 670-700us; FETCH_SIZE 54MB = 4.3x the 12.6MB footprint; staged bytes
// 1.6GB/dispatch served by L2+L3 at only 2.3 TB/s -> theory: default grid
// mixes all 4 batches on every XCD (12.4MB working set on 4MB L2) -> L2
// thrash, staging stream pinned on L3): XCD-AWARE BATCH-CLUSTERED SWIZZLE.
// 1-D grid of 512; xcd = lin&7 (observed round-robin), b = xcd>>1,
// qg = (lin>>3)|((lin&1)<<6) -- bijective; each XCD's blocks share one b so
// xs[b] (3.1MB) stays resident in its 4MB L2. Mapping drift affects speed
// only, never correctness. Selection math bit-identical to r3/r4/r5 passes.
// ---------------------------------------------------------------------------
__global__ __launch_bounds__(256, 2) void knn_kernel(
    const unsigned short* __restrict__ xs, const float* __restrict__ xx,
    int* __restrict__ fidx) {
  __shared__ __attribute__((aligned(16))) unsigned short atile[2][64 * 192]; // 49152 B
  __shared__ float cxx[2][64];                                               //   512 B
  __shared__ u64 abuf[4][64][BUFSZ];                                         // 30720 B
                                                                             // total 80384 B
  const int tid = threadIdx.x;
  const int w = tid >> 6;
  const int lane = tid & 63;
  const int r = lane & 15;    // query col (B) / cand row (A) within subtile
  const int g = lane >> 4;    // k-group
  // XCD-aware batch-clustered remap (see header comment)
  const int lin = blockIdx.x;
  const int xcd = lin & 7;
  const int b = xcd >> 1;
  const int qg = (lin >> 3) | ((xcd & 1) << 6);
  const int qbase = qg * 64 + w * 16;
  const int q = qbase + r;
  const char* xsb = ((const char*)xs) + (size_t)b * NN * 384;

  // query B-frags: bq[split][k-chunk]; lane holds k = (lane>>4)*8+[0..8) of 32
  bf16x8 bq[3][2];
  {
    const char* qrow = xsb + (size_t)q * 384;
    const int sw = (q & 7) << 4;
    #pragma unroll
    for (int s = 0; s < 3; ++s)
      #pragma unroll
      for (int c = 0; c < 2; ++c)
        bq[s][c] = *(const bf16x8*)(qrow + ((s * 128 + c * 64 + g * 16) ^ sw));
  }
  const float xxq = xx[b * NN + q];

  u64 tk[KK];
  #pragma unroll
  for (int j = 0; j < KK; ++j) tk[j] = INITKEY;
  float minv = -INFINITY;
  int cnt = 0;
  u64* mybuf = &abuf[w][lane][0];

  // stage tile t into buffer p
  auto stage = [&](int t, int p) {
    const char* src = xsb + (size_t)t * 64 * 384;
    char* dst = (char*)atile[p];
    #pragma unroll
    for (int it = 0; it < 6; ++it) {
      __builtin_amdgcn_global_load_lds(
          (gvoid*)(src + it * 4096 + tid * 16),
          (lvoid*)(dst + it * 4096 + tid * 16), 16, 0, 0);
    }
    if (tid < 16) {
      __builtin_amdgcn_global_load_lds(
          (gvoid*)(xx + b * NN + t * 64 + tid * 4),
          (lvoid*)(cxx[p] + tid * 4), 16, 0, 0);
    }
  };

  // fold buffered candidates into the register-sorted top-20, tighten minv
  auto rebuild = [&]() {
    int mxc = cnt;
    #pragma unroll
    for (int o = 32; o > 0; o >>= 1) {
      int v = __shfl_xor(mxc, o);
      mxc = mxc > v ? mxc : v;
    }
    for (int i = 0; i < mxc; ++i) {
      u64 k = (i < cnt) ? mybuf[i] : 0ULL;
      if (k > tk[KK - 1]) {
        #pragma unroll
        for (int jj = KK - 1; jj >= 1; --jj)
          tk[jj] = (k > tk[jj - 1]) ? tk[jj - 1] : ((k > tk[jj]) ? k : tk[jj]);
        tk[0] = (k > tk[0]) ? k : tk[0];
      }
    }
    cnt = 0;
    minv = keyval(tk[KK - 1]);
  };

  stage(0, 0);
  __syncthreads();

  for (int t = 0; t < NN / 64; ++t) {
    const int p = t & 1;
    if (t < NN / 64 - 1) stage(t + 1, p ^ 1);   // in flight during compute

    // --- hoist ALL subtile A-frags (24 ds_read_b128), c6-major ---
    const int sw = (r & 7) << 4;
    const char* tbase = (const char*)atile[p];
    bf16x8 a[4][6];
    #pragma unroll
    for (int c6 = 0; c6 < 6; ++c6) {
      const int off = (c6 * 64 + g * 16) ^ sw;
      #pragma unroll
      for (int ct = 0; ct < 4; ++ct)
        a[ct][c6] = *(const bf16x8*)(tbase + (ct * 16 + r) * 384 + off);
    }

    // --- 4 independent accumulator chains, interleaved (dep distance 4) ---
    f32x4 acc[4];
    #pragma unroll
    for (int ct = 0; ct < 4; ++ct) acc[ct] = (f32x4){0.f, 0.f, 0.f, 0.f};
    __builtin_amdgcn_s_setprio(1);
    #pragma unroll
    for (int s = 2; s >= 0; --s)       // b-split l,m first: small terms first
      #pragma unroll
      for (int c6 = 0; c6 < 6; ++c6) {
        const bf16x8 bqf = bq[s][c6 & 1];
        #pragma unroll
        for (int ct = 0; ct < 4; ++ct)
          acc[ct] = __builtin_amdgcn_mfma_f32_16x16x32_bf16(a[ct][c6], bqf,
                                                            acc[ct], 0, 0, 0);
      }
    __builtin_amdgcn_s_setprio(0);

    // --- pd + append (order identical to r3/r4/r5), rebuild between halves ---
    #pragma unroll
    for (int half = 0; half < 2; ++half) {
      #pragma unroll
      for (int cth = 0; cth < 2; ++cth) {
        const int ct = half * 2 + cth;
        #pragma unroll
        for (int j = 0; j < 4; ++j) {
          const int ml = ct * 16 + g * 4 + j;
          float pd = (-xxq - (-2.0f * acc[ct][j])) - cxx[p][ml];
          if (pd > minv) { mybuf[cnt] = packkey(pd, t * 64 + ml); ++cnt; }
        }
      }
      // invariant: cnt<=7 entering a subtile pair; <=8 appends per pair
      if (__any(cnt > 7)) rebuild();
    }
    __syncthreads();   // buf[p^1] now resident; buf[p] free for next stage
  }

  rebuild();   // flush remaining buffered candidates

  // --- epilogue: 4-way merge of the per-lane class lists -> fidx ---
  // scratch: atile is dead now (all waves passed the final barrier)
  u64* ml = ((u64*)&atile[0][0]) + (size_t)w * 64 * KK;   // 10240 B per wave
  #pragma unroll
  for (int j = 0; j < KK; ++j) ml[lane * KK + j] = tk[j];
  __syncthreads();
  if (lane < 16) {
    int* fo = fidx + ((size_t)b * NN + qbase + lane) * KK;
    const u64* L0 = ml + (lane + 0) * KK;
    const u64* L1 = ml + (lane + 16) * KK;
    const u64* L2 = ml + (lane + 32) * KK;
    const u64* L3 = ml + (lane + 48) * KK;
    int p0 = 0, p1 = 0, p2 = 0, p3 = 0;
    u64 h0 = L0[0], h1 = L1[0], h2 = L2[0], h3 = L3[0];
    #pragma unroll
    for (int k = 0; k < KK; ++k) {
      u64 bv = h0; int bc = 0;
      if (h1 > bv) { bv = h1; bc = 1; }
      if (h2 > bv) { bv = h2; bc = 2; }
      if (h3 > bv) { bv = h3; bc = 3; }
      fo[k] = (int)(~(unsigned)bv);
      if (bc == 0)      { ++p0; h0 = (p0 < KK) ? L0[p0] : 0ULL; }
      else if (bc == 1) { ++p1; h1 = (p1 < KK) ? L1[p1] : 0ULL; }
      else if (bc == 2) { ++p2; h2 = (p2 < KK) ? L2[p2] : 0ULL; }
      else              { ++p3; h3 = (p3 < KK) ? L3[p3] : 0ULL; }
    }
  }
}

// ---------------------------------------------------------------------------
// w1prep: pre-pack W1a^T as 3-way bf16-split MFMA B-frags. (unchanged)
// ---------------------------------------------------------------------------
__global__ __launch_bounds__(256) void w1prep_kernel(const float* __restrict__ W1,
                                                     unsigned short* __restrict__ w1p) {
  for (int e = threadIdx.x; e < 12288; e += 256) {
    const int f = e >> 9;
    const int rr = e & 511;
    const int l = rr >> 3;
    const int j = rr & 7;
    const int pair = f / 3, s = f % 3;
    const int dt = pair >> 1, kc = pair & 1;
    const int d = dt * 16 + (l & 15);
    const int c = kc * 32 + (l >> 4) * 8 + j;
    const float v = W1[d * DD + c];
    const unsigned short h = bf_rne(v);
    float r = v - bf_f(h);
    const unsigned short m = bf_rne(r);
    r -= bf_f(m);
    const unsigned short lo = bf_rne(r);
    w1p[(size_t)f * 512 + l * 8 + j] = (s == 0) ? h : ((s == 1) ? m : lo);
  }
}

#define MFMA16(A, B, C) __builtin_amdgcn_mfma_f32_16x16x32_bf16((A), (B), (C), 0, 0, 0)

// one h-GEMM cross term (SA = A split, SB = B split), indices compile-time
template <int SA, int SB>
__device__ __forceinline__ void h_term(const bf16x8 (&a)[3][2][2],
                                       const bf16x8 (&w1f)[24],
                                       f32x4 (&acc)[4][2]) {
  #pragma unroll
  for (int dt = 0; dt < 4; ++dt)
    #pragma unroll
    for (int kc = 0; kc < 2; ++kc) {
      const bf16x8 bf = w1f[(dt * 2 + kc) * 3 + SB];
      acc[dt][0] = MFMA16(a[SA][kc][0], bf, acc[dt][0]);
      acc[dt][1] = MFMA16(a[SA][kc][1], bf, acc[dt][1]);
    }
}

// epilogue for d-tile DT: Y re-layout via identity-B MFMA, masked softmax
// over k (shfl_xor across the 4 lane-groups), returns T[d] = sum_k y_k[d]*gate
template <int DT>
__device__ __forceinline__ float d1_epi(const bf16x8 (&a)[3][2][2],
                                        bf16x8 id0, bf16x8 id1,
                                        const f32x4 (&acc)[4][2], int g) {
  constexpr int KC = DT >> 1;
  const bf16x8 idp = (DT & 1) ? id1 : id0;
  f32x4 yf0 = {0.f, 0.f, 0.f, 0.f}, yf1 = {0.f, 0.f, 0.f, 0.f};
  yf0 = MFMA16(a[1][KC][0], idp, yf0);   // m split first (smaller)
  yf0 = MFMA16(a[0][KC][0], idp, yf0);
  yf1 = MFMA16(a[1][KC][1], idp, yf1);
  yf1 = MFMA16(a[0][KC][1], idp, yf1);
  const f32x4 h0 = acc[DT][0], h1 = acc[DT][1];
  float mx = fmaxf(fmaxf(h0[0], h0[1]), fmaxf(h0[2], h0[3]));
  mx = fmaxf(mx, fmaxf(fmaxf(h1[0], h1[1]), fmaxf(h1[2], h1[3])));  // dups harmless
  mx = fmaxf(mx, __shfl_xor(mx, 16));
  mx = fmaxf(mx, __shfl_xor(mx, 32));
  float sl = 0.f, tl = 0.f;
  #pragma unroll
  for (int j = 0; j < 4; ++j) {
    const float e = __expf(h0[j] - mx);
    sl += e; tl += yf0[j] * e;
  }
  if (g == 0) {   // tile1 rows k=16..19 counted exactly once (dup groups masked)
    #pragma unroll
    for (int j = 0; j < 4; ++j) {
      const float e = __expf(h1[j] - mx);
      sl += e; tl += yf1[j] * e;
    }
  }
  sl += __shfl_xor(sl, 16); sl += __shfl_xor(sl, 32);
  tl += __shfl_xor(tl, 16); tl += __shfl_xor(tl, 32);
  return tl / sl;
}

// ---------------------------------------------------------------------------
// d1 (MFMA rewrite; unchanged from round-3 pass).
//   td = z.(W1b-W1a) is k-constant -> cancels in softmax(axis=k): DROPPED.
//   sum_k gate[k][d] = 1 -> g[d>=64] = z[d-64]; g[d<64] = (sum_k y_k[d]*gate)
//   - z[d]. One wave per n, no LDS, no barriers.
// ---------------------------------------------------------------------------
__global__ __launch_bounds__(256, 2) void d1_kernel(
    const unsigned short* __restrict__ xs, const int* __restrict__ fidx,
    const unsigned short* __restrict__ w1p, float* __restrict__ gbuf) {
  const int tid = threadIdx.x;
  const int w = tid >> 6;
  const int lane = tid & 63;
  const int r = lane & 15;
  const int g = lane >> 4;
  const int b = blockIdx.y;
  const char* xsb = ((const char*)xs) + (size_t)b * NN * 384;

  // hoisted n-invariant B-frags (96 VGPR)
  bf16x8 w1f[24];
  #pragma unroll
  for (int f = 0; f < 24; ++f)
    w1f[f] = *(const bf16x8*)(((const char*)w1p) + f * 1024 + lane * 16);

  // identity B-frags: select cols [p*16, p*16+16) of the K=32 chunk
  bf16x8 id0, id1;
  #pragma unroll
  for (int j = 0; j < 8; ++j) {
    id0[j] = (g == (r >> 3) && j == (r & 7)) ? (short)0x3F80 : (short)0;
    id1[j] = (g == 2 + (r >> 3) && j == (r & 7)) ? (short)0x3F80 : (short)0;
  }

  for (int i = 0; i < 4; ++i) {
    const int n = blockIdx.x * 16 + w * 4 + i;
    const size_t ng = (size_t)b * NN + n;
    const int* kp = fidx + ng * KK;
    const int row0 = kp[r];                 // tile0 row r -> neighbor r
    const int row1 = kp[16 + (r & 3)];      // tile1 row r -> neighbor 16+(r&3)
    const char* rp0 = xsb + (size_t)row0 * 384;
    const char* rp1 = xsb + (size_t)row1 * 384;
    const int sw0 = (row0 & 7) << 4, sw1 = (row1 & 7) << 4;

    bf16x8 a[3][2][2];
    #pragma unroll
    for (int s = 0; s < 3; ++s)
      #pragma unroll
      for (int kc = 0; kc < 2; ++kc) {
        const int off = s * 128 + kc * 64 + g * 16;
        a[s][kc][0] = *(const bf16x8*)(rp0 + (off ^ sw0));
        a[s][kc][1] = *(const bf16x8*)(rp1 + (off ^ sw1));
      }

    // z[c=lane] reconstructed to ~2^-27
    const char* zrow = xsb + (size_t)n * 384;
    const int swn = (n & 7) << 4;
    float zl;
    {
      const unsigned short zh = *(const unsigned short*)(zrow + ((2 * lane) ^ swn));
      const unsigned short zm = *(const unsigned short*)(zrow + ((128 + 2 * lane) ^ swn));
      const unsigned short zo = *(const unsigned short*)(zrow + ((256 + 2 * lane) ^ swn));
      zl = bf_f(zh) + bf_f(zm) + bf_f(zo);
    }

    f32x4 acc[4][2];
    #pragma unroll
    for (int dt = 0; dt < 4; ++dt) {
      acc[dt][0] = (f32x4){0.f, 0.f, 0.f, 0.f};
      acc[dt][1] = (f32x4){0.f, 0.f, 0.f, 0.f};
    }
    // smallest cross terms first
    h_term<2, 0>(a, w1f, acc);
    h_term<0, 2>(a, w1f, acc);
    h_term<1, 1>(a, w1f, acc);
    h_term<1, 0>(a, w1f, acc);
    h_term<0, 1>(a, w1f, acc);
    h_term<0, 0>(a, w1f, acc);

    const float t0 = d1_epi<0>(a, id0, id1, acc, g);
    const float t1 = d1_epi<1>(a, id0, id1, acc, g);
    const float t2 = d1_epi<2>(a, id0, id1, acc, g);
    const float t3 = d1_epi<3>(a, id0, id1, acc, g);

    float* go = gbuf + ng * DD;
    go[64 + lane] = zl;                     // g[d>=64] = z  (sum gate == 1)
    const float z0 = __shfl(zl, r);
    const float z1 = __shfl(zl, 16 + r);
    const float z2 = __shfl(zl, 32 + r);
    const float z3 = __shfl(zl, 48 + r);
    if (lane < 16) {
      go[r]      = t0 - z0;
      go[16 + r] = t1 - z1;
      go[32 + r] = t2 - z2;
      go[48 + r] = t3 - z3;
    }
  }
}

// ---------------------------------------------------------------------------
// d2: out[b][o][n] = sum_c g[b][n][c] * W2[o][c]. (unchanged)
// ---------------------------------------------------------------------------
__global__ __launch_bounds__(256) void d2_kernel(const float* __restrict__ gbuf,
                                                 const float* __restrict__ W2,
                                                 float* __restrict__ out) {
  __shared__ float4 w2s[OO * 32];  // addr4 = o*32 + (c4 ^ (o&7))
  const int tid = threadIdx.x;
  const int b = blockIdx.y;
  const int n0 = blockIdx.x * 32;
  const float4* w2v = (const float4*)W2;
  for (int t = tid; t < OO * 32; t += 256) {
    int o = t >> 5, c4 = t & 31;
    w2s[o * 32 + (c4 ^ (o & 7))] = w2v[t];
  }
  __syncthreads();
  const int og = tid & 7;
  const int ni = tid >> 3;
  const int n = n0 + ni;
  const float4* gp = (const float4*)(gbuf + ((size_t)b * NN + n) * DD);
  float acc[16];
  #pragma unroll
  for (int j = 0; j < 16; ++j) acc[j] = 0.0f;
  for (int c4 = 0; c4 < 32; ++c4) {
    float4 g4 = gp[c4];
    #pragma unroll
    for (int j = 0; j < 16; ++j) {
      const int o = j * 8 + og;
      float4 w4 = w2s[o * 32 + (c4 ^ og)];
      acc[j] += g4.x * w4.x + g4.y * w4.y + g4.z * w4.z + g4.w * w4.w;
    }
  }
  float* outb = out + (size_t)b * OO * NN;
  #pragma unroll
  for (int j = 0; j < 16; ++j) {
    outb[(size_t)(j * 8 + og) * NN + n] = acc[j];
  }
}

// ---------------------------------------------------------------------------
// ws layout (bytes):
//   xs   @ 0          : 6,291,456 u16 = 12,582,912 B  (live: prep->knn,d1)
//   xx   @ 12,582,912 :    32,768 f32 =    131,072 B  (live: prep->knn)
//   w1p  @ 12,582,912 :    12,288 u16 =     24,576 B  (aliases dead xx; w1prep->d1)
//   fidx @ 12,713,984 :   655,360 i32 =  2,621,440 B  (live: knn->d1)
//   gbuf @ 15,335,424 : 4,194,304 f32 = 16,777,216 B  (live: d1->d2)
// total: 32,112,640 B
// ---------------------------------------------------------------------------
extern "C" void kernel_launch(void* const* d_in, const int* in_sizes, int n_in,
                              void* d_out, int out_size, void* d_ws, size_t ws_size,
                              hipStream_t stream) {
  const float* x  = (const float*)d_in[0];
  const float* W1 = (const float*)d_in[1];
  const float* W2 = (const float*)d_in[2];
  float* out = (float*)d_out;
  char* ws = (char*)d_ws;
  unsigned short* xs = (unsigned short*)(ws);
  float* xx = (float*)(ws + 12582912);
  unsigned short* w1p = (unsigned short*)(ws + 12582912);
  int* fidx = (int*)(ws + 12713984);
  float* gbuf = (float*)(ws + 15335424);

  prep_kernel<<<dim3(NN / 128, BB), 128, 0, stream>>>(x, xx, xs);
  knn_kernel<<<dim3(512), 256, 0, stream>>>(xs, xx, fidx);   // 1-D: XCD swizzle
  w1prep_kernel<<<dim3(1), 256, 0, stream>>>(W1, w1p);       // after knn: xx dead
  d1_kernel<<<dim3(NN / 16, BB), 256, 0, stream>>>(xs, fidx, w1p, gbuf);
  d2_kernel<<<dim3(NN / 32, BB), 256, 0, stream>>>(gbuf, W2, out);
}

// Round 7
// 708.310 us; speedup vs baseline: 1.1657x; 1.1583x over previous
//
#include <hip/hip_runtime.h>
#include <math.h>

#define BB 4
#define CC 64
#define NN 8192
#define OO 128
#define KK 20
#define DD 128            // 2*CC
#define NT 64             // tiles per chunk sweep (4096 candidates / 64)
#define BUFSZ 10          // per-lane append buffer; checked after every subtile (T=6, +4 -> <=10)

typedef short bf16x8 __attribute__((ext_vector_type(8)));   // 8 bf16 (4 VGPR)
typedef float f32x4 __attribute__((ext_vector_type(4)));
typedef unsigned short u16x8 __attribute__((ext_vector_type(8)));
typedef unsigned long long u64;

typedef __attribute__((address_space(1))) const void gvoid;
typedef __attribute__((address_space(3))) void lvoid;

// orderable-key packing: (float value, candidate idx) -> u64, so that
// u64-descending == (value desc, idx asc). Matches jax.lax.top_k tie-breaking.
__device__ __forceinline__ u64 packkey(float v, int idx) {
  unsigned u = __float_as_uint(v);
  unsigned o = ((int)u < 0) ? ~u : (u | 0x80000000u);
  return (((u64)o) << 32) | (unsigned)(~idx);
}
__device__ __forceinline__ float keyval(u64 k) {
  unsigned o = (unsigned)(k >> 32);
  unsigned u = (o & 0x80000000u) ? (o ^ 0x80000000u) : ~o;
  return __uint_as_float(u);
}
#define INITKEY (((u64)0x007FFFFFu) << 32)   // packkey(-inf, 0xFFFFFFFF)

__device__ __forceinline__ unsigned short bf_rne(float f) {
  unsigned u = __float_as_uint(f);
  u += 0x7FFFu + ((u >> 16) & 1u);
  return (unsigned short)(u >> 16);
}
__device__ __forceinline__ float bf_f(unsigned short h) {
  return __uint_as_float(((unsigned)h) << 16);
}

// ---------------------------------------------------------------------------
// prep: xx[b][n] and xs[b][n][192] = 3-way bf16 split [h(64)|m(64)|l(64)],
// PRE-SWIZZLED: 16B-group at logical byte o lands at o ^ ((n&7)<<4).
// (unchanged)
// ---------------------------------------------------------------------------
__global__ __launch_bounds__(128) void prep_kernel(const float* __restrict__ x,
                                                   float* __restrict__ xx,
                                                   unsigned short* __restrict__ xs) {
  const int tid = threadIdx.x;
  const int b = blockIdx.y;
  const int n0 = blockIdx.x * 128;
  const float* xb = x + (size_t)b * CC * NN;
  float xv[CC];
  float acc = 0.0f;
  #pragma unroll
  for (int c = 0; c < CC; ++c) {
    float v = xb[(size_t)c * NN + n0 + tid];   // coalesced over tid
    acc += v * v;
    xv[c] = v;
  }
  xx[b * NN + n0 + tid] = acc;

  const int n = n0 + tid;
  char* xsrow = ((char*)xs) + ((size_t)b * NN + n) * 384;
  const int swn = (n & 7) << 4;
  #pragma unroll
  for (int gr = 0; gr < 8; ++gr) {
    u16x8 h8, m8, l8;
    #pragma unroll
    for (int e = 0; e < 8; ++e) {
      float v = xv[gr * 8 + e];
      unsigned short h = bf_rne(v);
      float r = v - bf_f(h);
      unsigned short m = bf_rne(r);
      r -= bf_f(m);
      unsigned short l = bf_rne(r);
      h8[e] = (unsigned short)h; m8[e] = m; l8[e] = l;
    }
    *(u16x8*)(xsrow + (((gr * 16) + 0) ^ swn)) = h8;
    *(u16x8*)(xsrow + (((gr * 16) + 128) ^ swn)) = m8;
    *(u16x8*)(xsrow + (((gr * 16) + 256) ^ swn)) = l8;
  }
}

// ---------------------------------------------------------------------------
// knn: MFMA distance matrix + per-lane buffered top-20.
// ROUND-7 CHANGE (post-mortem r3-r6: 4 orthogonal levers all ~695us, all
// pipes <30%, FETCH collapsed with no time change -> concurrency-starved at
// the invariant 8 waves/CU): SPLIT CANDIDATE SWEEP (NCH=2). Grid 1024 blocks
// -> 16 waves/CU AND halved per-wave serial work. LDS dieted to 40192 B for
// 4 blocks/CU: single-buffered atile (dbuf proven neutral r3==r4), split
// pd(f32)/idx(u16) buffers BUFSZ=10, threshold check after EVERY subtile
// (trigger cnt>6; rebuild points don't affect the selected set - keys are
// totally ordered). Per-subtile MFMA chain bit-identical to r3-r6. Each
// block 4-way-merges its class lists in-block (two-pass, atile scratch) to
// per-(query,chunk) sorted u64 top-20; tiny 2-way merge kernel -> fidx.
// XCD map: b=(lin&7)>>1, ch=lin&1 -> each XCD serves one (batch,chunk):
// 1.5MB candidate set, L2-resident.
// ---------------------------------------------------------------------------
__global__ __launch_bounds__(256, 4) void knn_kernel(
    const unsigned short* __restrict__ xs, const float* __restrict__ xx,
    u64* __restrict__ pkeys) {
  __shared__ __attribute__((aligned(16))) unsigned short atile[64 * 192]; // 24576 B
  __shared__ float pdb[4][64][BUFSZ];                                     // 10240 B
  __shared__ unsigned short idb[4][64][BUFSZ];                            //  5120 B
  __shared__ float cxx[64];                                               //   256 B
                                                                          // 40192 B total
  const int tid = threadIdx.x;
  const int w = tid >> 6;
  const int lane = tid & 63;
  const int r = lane & 15;    // query col (B) / cand row (A) within subtile
  const int g = lane >> 4;    // k-group
  // XCD-aware map: lin = qg*8 + b*2 + ch (bijective over 1024)
  const int lin = blockIdx.x;
  const int b = (lin & 7) >> 1;
  const int ch = lin & 1;
  const int qg = lin >> 3;           // [0,128)
  const int qbase = qg * 64 + w * 16;
  const int q = qbase + r;
  const int cbase = ch * 4096;
  const char* xsb = ((const char*)xs) + (size_t)b * NN * 384;

  // query B-frags: bq[split][k-chunk]; lane holds k = (lane>>4)*8+[0..8) of 32
  bf16x8 bq[3][2];
  {
    const char* qrow = xsb + (size_t)q * 384;
    const int sw = (q & 7) << 4;
    #pragma unroll
    for (int s = 0; s < 3; ++s)
      #pragma unroll
      for (int c = 0; c < 2; ++c)
        bq[s][c] = *(const bf16x8*)(qrow + ((s * 128 + c * 64 + g * 16) ^ sw));
  }
  const float xxq = xx[b * NN + q];

  u64 tk[KK];
  #pragma unroll
  for (int j = 0; j < KK; ++j) tk[j] = INITKEY;
  float minv = -INFINITY;
  int cnt = 0;
  float* pdl = &pdb[w][lane][0];
  unsigned short* idl = &idb[w][lane][0];

  // stage tile t (single buffer, r3-proven shape)
  auto stage = [&](int t) {
    const char* src = xsb + (size_t)(cbase + t * 64) * 384;
    char* dst = (char*)atile;
    #pragma unroll
    for (int it = 0; it < 6; ++it) {
      __builtin_amdgcn_global_load_lds(
          (gvoid*)(src + it * 4096 + tid * 16),
          (lvoid*)(dst + it * 4096 + tid * 16), 16, 0, 0);
    }
    if (tid < 16) {
      __builtin_amdgcn_global_load_lds(
          (gvoid*)(xx + b * NN + cbase + t * 64 + tid * 4),
          (lvoid*)(cxx + tid * 4), 16, 0, 0);
    }
  };

  // fold buffered candidates into the register-sorted top-20, tighten minv
  auto rebuild = [&]() {
    int mxc = cnt;
    #pragma unroll
    for (int o = 32; o > 0; o >>= 1) {
      int v = __shfl_xor(mxc, o);
      mxc = mxc > v ? mxc : v;
    }
    for (int i = 0; i < mxc; ++i) {
      u64 k = (i < cnt) ? packkey(pdl[i], (int)idl[i]) : 0ULL;
      if (k > tk[KK - 1]) {
        #pragma unroll
        for (int jj = KK - 1; jj >= 1; --jj)
          tk[jj] = (k > tk[jj - 1]) ? tk[jj - 1] : ((k > tk[jj]) ? k : tk[jj]);
        tk[0] = (k > tk[0]) ? k : tk[0];
      }
    }
    cnt = 0;
    minv = keyval(tk[KK - 1]);
  };

  for (int t = 0; t < NT; ++t) {
    stage(t);
    __syncthreads();   // vmcnt drained by compiler before barrier

    #pragma unroll
    for (int ct = 0; ct < 4; ++ct) {
      const char* arow = ((const char*)atile) + (ct * 16 + r) * 384;
      const int sw = (r & 7) << 4;
      bf16x8 a6[6];
      #pragma unroll
      for (int c6 = 0; c6 < 6; ++c6)
        a6[c6] = *(const bf16x8*)(arow + ((c6 * 64 + g * 16) ^ sw));
      f32x4 acc = {0.f, 0.f, 0.f, 0.f};
      __builtin_amdgcn_s_setprio(1);
      #pragma unroll
      for (int s = 2; s >= 0; --s)   // b-split l,m first: small terms first
        #pragma unroll
        for (int c6 = 0; c6 < 6; ++c6)
          acc = __builtin_amdgcn_mfma_f32_16x16x32_bf16(a6[c6], bq[s][c6 & 1],
                                                        acc, 0, 0, 0);
      __builtin_amdgcn_s_setprio(0);
      #pragma unroll
      for (int j = 0; j < 4; ++j) {
        const int ml = ct * 16 + g * 4 + j;
        float pd = (-xxq - (-2.0f * acc[j])) - cxx[ml];
        if (pd > minv) {
          pdl[cnt] = pd;
          idl[cnt] = (unsigned short)(cbase + t * 64 + ml);
          ++cnt;
        }
      }
      // invariant: cnt<=6 entering a subtile; +4 appends -> <=10 = BUFSZ
      if (__any(cnt > 6)) rebuild();
    }
    __syncthreads();   // atile consumed; next stage may overwrite
  }

  rebuild();   // flush remaining buffered candidates

  // --- epilogue: two-pass 4-way in-block merge -> pkeys[q][ch][20] ---
  // atile is dead; 2 waves at a time use disjoint 10240-B scratch regions.
  for (int pass = 0; pass < 2; ++pass) {
    if (pass) __syncthreads();
    if ((w >> 1) == pass) {
      u64* ml = ((u64*)atile) + (size_t)(w & 1) * 64 * KK;
      #pragma unroll
      for (int j = 0; j < KK; ++j) ml[lane * KK + j] = tk[j];
      // same-wave LDS write->read: in-order, compiler inserts lgkmcnt
      if (lane < 16) {
        u64* po = pkeys + (((size_t)b * NN + qbase + lane) * 2 + ch) * KK;
        const u64* L0 = ml + (lane + 0) * KK;
        const u64* L1 = ml + (lane + 16) * KK;
        const u64* L2 = ml + (lane + 32) * KK;
        const u64* L3 = ml + (lane + 48) * KK;
        int p0 = 0, p1 = 0, p2 = 0, p3 = 0;
        u64 h0 = L0[0], h1 = L1[0], h2 = L2[0], h3 = L3[0];
        #pragma unroll
        for (int k = 0; k < KK; ++k) {
          u64 bv = h0; int bc = 0;
          if (h1 > bv) { bv = h1; bc = 1; }
          if (h2 > bv) { bv = h2; bc = 2; }
          if (h3 > bv) { bv = h3; bc = 3; }
          po[k] = bv;
          if (bc == 0)      { ++p0; h0 = (p0 < KK) ? L0[p0] : 0ULL; }
          else if (bc == 1) { ++p1; h1 = (p1 < KK) ? L1[p1] : 0ULL; }
          else if (bc == 2) { ++p2; h2 = (p2 < KK) ? L2[p2] : 0ULL; }
          else              { ++p3; h3 = (p3 < KK) ? L3[p3] : 0ULL; }
        }
      }
    }
  }
}

// ---------------------------------------------------------------------------
// merge: per query, 2-way merge of the two chunk lists (sorted desc u64).
// Chunks partition index ranges; u64 compare embeds (value desc, idx asc).
// ---------------------------------------------------------------------------
__global__ __launch_bounds__(256) void merge_kernel(const u64* __restrict__ pkeys,
                                                    int* __restrict__ fidx) {
  const int q = blockIdx.x * 256 + threadIdx.x;   // q = b*NN + n
  const u64* pk = pkeys + (size_t)q * 2 * KK;
  int* fo = fidx + (size_t)q * KK;
  int p0 = 0, p1 = 0;
  u64 h0 = pk[0], h1 = pk[KK];
  #pragma unroll
  for (int k = 0; k < KK; ++k) {
    const bool t1 = h1 > h0;
    const u64 bv = t1 ? h1 : h0;
    fo[k] = (int)(~(unsigned)bv);
    if (t1) { ++p1; h1 = (p1 < KK) ? pk[KK + p1] : 0ULL; }
    else    { ++p0; h0 = (p0 < KK) ? pk[p0] : 0ULL; }
  }
}

// ---------------------------------------------------------------------------
// w1prep: pre-pack W1a^T as 3-way bf16-split MFMA B-frags. (unchanged)
// ---------------------------------------------------------------------------
__global__ __launch_bounds__(256) void w1prep_kernel(const float* __restrict__ W1,
                                                     unsigned short* __restrict__ w1p) {
  for (int e = threadIdx.x; e < 12288; e += 256) {
    const int f = e >> 9;
    const int rr = e & 511;
    const int l = rr >> 3;
    const int j = rr & 7;
    const int pair = f / 3, s = f % 3;
    const int dt = pair >> 1, kc = pair & 1;
    const int d = dt * 16 + (l & 15);
    const int c = kc * 32 + (l >> 4) * 8 + j;
    const float v = W1[d * DD + c];
    const unsigned short h = bf_rne(v);
    float r = v - bf_f(h);
    const unsigned short m = bf_rne(r);
    r -= bf_f(m);
    const unsigned short lo = bf_rne(r);
    w1p[(size_t)f * 512 + l * 8 + j] = (s == 0) ? h : ((s == 1) ? m : lo);
  }
}

#define MFMA16(A, B, C) __builtin_amdgcn_mfma_f32_16x16x32_bf16((A), (B), (C), 0, 0, 0)

// one h-GEMM cross term (SA = A split, SB = B split), indices compile-time
template <int SA, int SB>
__device__ __forceinline__ void h_term(const bf16x8 (&a)[3][2][2],
                                       const bf16x8 (&w1f)[24],
                                       f32x4 (&acc)[4][2]) {
  #pragma unroll
  for (int dt = 0; dt < 4; ++dt)
    #pragma unroll
    for (int kc = 0; kc < 2; ++kc) {
      const bf16x8 bf = w1f[(dt * 2 + kc) * 3 + SB];
      acc[dt][0] = MFMA16(a[SA][kc][0], bf, acc[dt][0]);
      acc[dt][1] = MFMA16(a[SA][kc][1], bf, acc[dt][1]);
    }
}

// epilogue for d-tile DT: Y re-layout via identity-B MFMA, masked softmax
// over k (shfl_xor across the 4 lane-groups), returns T[d] = sum_k y_k[d]*gate
template <int DT>
__device__ __forceinline__ float d1_epi(const bf16x8 (&a)[3][2][2],
                                        bf16x8 id0, bf16x8 id1,
                                        const f32x4 (&acc)[4][2], int g) {
  constexpr int KC = DT >> 1;
  const bf16x8 idp = (DT & 1) ? id1 : id0;
  f32x4 yf0 = {0.f, 0.f, 0.f, 0.f}, yf1 = {0.f, 0.f, 0.f, 0.f};
  yf0 = MFMA16(a[1][KC][0], idp, yf0);   // m split first (smaller)
  yf0 = MFMA16(a[0][KC][0], idp, yf0);
  yf1 = MFMA16(a[1][KC][1], idp, yf1);
  yf1 = MFMA16(a[0][KC][1], idp, yf1);
  const f32x4 h0 = acc[DT][0], h1 = acc[DT][1];
  float mx = fmaxf(fmaxf(h0[0], h0[1]), fmaxf(h0[2], h0[3]));
  mx = fmaxf(mx, fmaxf(fmaxf(h1[0], h1[1]), fmaxf(h1[2], h1[3])));  // dups harmless
  mx = fmaxf(mx, __shfl_xor(mx, 16));
  mx = fmaxf(mx, __shfl_xor(mx, 32));
  float sl = 0.f, tl = 0.f;
  #pragma unroll
  for (int j = 0; j < 4; ++j) {
    const float e = __expf(h0[j] - mx);
    sl += e; tl += yf0[j] * e;
  }
  if (g == 0) {   // tile1 rows k=16..19 counted exactly once (dup groups masked)
    #pragma unroll
    for (int j = 0; j < 4; ++j) {
      const float e = __expf(h1[j] - mx);
      sl += e; tl += yf1[j] * e;
    }
  }
  sl += __shfl_xor(sl, 16); sl += __shfl_xor(sl, 32);
  tl += __shfl_xor(tl, 16); tl += __shfl_xor(tl, 32);
  return tl / sl;
}

// ---------------------------------------------------------------------------
// d1 (MFMA rewrite; unchanged from round-3 pass).
// ---------------------------------------------------------------------------
__global__ __launch_bounds__(256, 2) void d1_kernel(
    const unsigned short* __restrict__ xs, const int* __restrict__ fidx,
    const unsigned short* __restrict__ w1p, float* __restrict__ gbuf) {
  const int tid = threadIdx.x;
  const int w = tid >> 6;
  const int lane = tid & 63;
  const int r = lane & 15;
  const int g = lane >> 4;
  const int b = blockIdx.y;
  const char* xsb = ((const char*)xs) + (size_t)b * NN * 384;

  // hoisted n-invariant B-frags (96 VGPR)
  bf16x8 w1f[24];
  #pragma unroll
  for (int f = 0; f < 24; ++f)
    w1f[f] = *(const bf16x8*)(((const char*)w1p) + f * 1024 + lane * 16);

  // identity B-frags: select cols [p*16, p*16+16) of the K=32 chunk
  bf16x8 id0, id1;
  #pragma unroll
  for (int j = 0; j < 8; ++j) {
    id0[j] = (g == (r >> 3) && j == (r & 7)) ? (short)0x3F80 : (short)0;
    id1[j] = (g == 2 + (r >> 3) && j == (r & 7)) ? (short)0x3F80 : (short)0;
  }

  for (int i = 0; i < 4; ++i) {
    const int n = blockIdx.x * 16 + w * 4 + i;
    const size_t ng = (size_t)b * NN + n;
    const int* kp = fidx + ng * KK;
    const int row0 = kp[r];                 // tile0 row r -> neighbor r
    const int row1 = kp[16 + (r & 3)];      // tile1 row r -> neighbor 16+(r&3)
    const char* rp0 = xsb + (size_t)row0 * 384;
    const char* rp1 = xsb + (size_t)row1 * 384;
    const int sw0 = (row0 & 7) << 4, sw1 = (row1 & 7) << 4;

    bf16x8 a[3][2][2];
    #pragma unroll
    for (int s = 0; s < 3; ++s)
      #pragma unroll
      for (int kc = 0; kc < 2; ++kc) {
        const int off = s * 128 + kc * 64 + g * 16;
        a[s][kc][0] = *(const bf16x8*)(rp0 + (off ^ sw0));
        a[s][kc][1] = *(const bf16x8*)(rp1 + (off ^ sw1));
      }

    // z[c=lane] reconstructed to ~2^-27
    const char* zrow = xsb + (size_t)n * 384;
    const int swn = (n & 7) << 4;
    float zl;
    {
      const unsigned short zh = *(const unsigned short*)(zrow + ((2 * lane) ^ swn));
      const unsigned short zm = *(const unsigned short*)(zrow + ((128 + 2 * lane) ^ swn));
      const unsigned short zo = *(const unsigned short*)(zrow + ((256 + 2 * lane) ^ swn));
      zl = bf_f(zh) + bf_f(zm) + bf_f(zo);
    }

    f32x4 acc[4][2];
    #pragma unroll
    for (int dt = 0; dt < 4; ++dt) {
      acc[dt][0] = (f32x4){0.f, 0.f, 0.f, 0.f};
      acc[dt][1] = (f32x4){0.f, 0.f, 0.f, 0.f};
    }
    // smallest cross terms first
    h_term<2, 0>(a, w1f, acc);
    h_term<0, 2>(a, w1f, acc);
    h_term<1, 1>(a, w1f, acc);
    h_term<1, 0>(a, w1f, acc);
    h_term<0, 1>(a, w1f, acc);
    h_term<0, 0>(a, w1f, acc);

    const float t0 = d1_epi<0>(a, id0, id1, acc, g);
    const float t1 = d1_epi<1>(a, id0, id1, acc, g);
    const float t2 = d1_epi<2>(a, id0, id1, acc, g);
    const float t3 = d1_epi<3>(a, id0, id1, acc, g);

    float* go = gbuf + ng * DD;
    go[64 + lane] = zl;                     // g[d>=64] = z  (sum gate == 1)
    const float z0 = __shfl(zl, r);
    const float z1 = __shfl(zl, 16 + r);
    const float z2 = __shfl(zl, 32 + r);
    const float z3 = __shfl(zl, 48 + r);
    if (lane < 16) {
      go[r]      = t0 - z0;
      go[16 + r] = t1 - z1;
      go[32 + r] = t2 - z2;
      go[48 + r] = t3 - z3;
    }
  }
}

// ---------------------------------------------------------------------------
// d2: out[b][o][n] = sum_c g[b][n][c] * W2[o][c]. (unchanged)
// ---------------------------------------------------------------------------
__global__ __launch_bounds__(256) void d2_kernel(const float* __restrict__ gbuf,
                                                 const float* __restrict__ W2,
                                                 float* __restrict__ out) {
  __shared__ float4 w2s[OO * 32];  // addr4 = o*32 + (c4 ^ (o&7))
  const int tid = threadIdx.x;
  const int b = blockIdx.y;
  const int n0 = blockIdx.x * 32;
  const float4* w2v = (const float4*)W2;
  for (int t = tid; t < OO * 32; t += 256) {
    int o = t >> 5, c4 = t & 31;
    w2s[o * 32 + (c4 ^ (o & 7))] = w2v[t];
  }
  __syncthreads();
  const int og = tid & 7;
  const int ni = tid >> 3;
  const int n = n0 + ni;
  const float4* gp = (const float4*)(gbuf + ((size_t)b * NN + n) * DD);
  float acc[16];
  #pragma unroll
  for (int j = 0; j < 16; ++j) acc[j] = 0.0f;
  for (int c4 = 0; c4 < 32; ++c4) {
    float4 g4 = gp[c4];
    #pragma unroll
    for (int j = 0; j < 16; ++j) {
      const int o = j * 8 + og;
      float4 w4 = w2s[o * 32 + (c4 ^ og)];
      acc[j] += g4.x * w4.x + g4.y * w4.y + g4.z * w4.z + g4.w * w4.w;
    }
  }
  float* outb = out + (size_t)b * OO * NN;
  #pragma unroll
  for (int j = 0; j < 16; ++j) {
    outb[(size_t)(j * 8 + og) * NN + n] = acc[j];
  }
}

// ---------------------------------------------------------------------------
// ws layout (bytes):
//   xs    @ 0          : 6,291,456 u16 = 12,582,912 B  (live: prep->knn,d1)
//   xx    @ 12,582,912 :    32,768 f32 =    131,072 B  (live: prep->knn)
//   w1p   @ 12,582,912 :    12,288 u16 =     24,576 B  (aliases dead xx; w1prep->d1)
//   fidx  @ 12,713,984 :   655,360 i32 =  2,621,440 B  (live: merge->d1)
//   pkeys @ 15,335,424 : 1,310,720 u64 = 10,485,760 B  (live: knn->merge; front of gbuf)
//   gbuf  @ 15,335,424 : 4,194,304 f32 = 16,777,216 B  (live: d1->d2; reuses pkeys)
// total: 32,112,640 B
// ---------------------------------------------------------------------------
extern "C" void kernel_launch(void* const* d_in, const int* in_sizes, int n_in,
                              void* d_out, int out_size, void* d_ws, size_t ws_size,
                              hipStream_t stream) {
  const float* x  = (const float*)d_in[0];
  const float* W1 = (const float*)d_in[1];
  const float* W2 = (const float*)d_in[2];
  float* out = (float*)d_out;
  char* ws = (char*)d_ws;
  unsigned short* xs = (unsigned short*)(ws);
  float* xx = (float*)(ws + 12582912);
  unsigned short* w1p = (unsigned short*)(ws + 12582912);
  int* fidx = (int*)(ws + 12713984);
  u64* pkeys = (u64*)(ws + 15335424);
  float* gbuf = (float*)(ws + 15335424);

  prep_kernel<<<dim3(NN / 128, BB), 128, 0, stream>>>(x, xx, xs);
  knn_kernel<<<dim3(1024), 256, 0, stream>>>(xs, xx, pkeys);   // 16 waves/CU
  merge_kernel<<<dim3(BB * NN / 256), 256, 0, stream>>>(pkeys, fidx);
  w1prep_kernel<<<dim3(1), 256, 0, stream>>>(W1, w1p);         // after knn: xx dead
  d1_kernel<<<dim3(NN / 16, BB), 256, 0, stream>>>(xs, fidx, w1p, gbuf);
  d2_kernel<<<dim3(NN / 32, BB), 256, 0, stream>>>(gbuf, W2, out);
}